// Round 1
// baseline (796.163 us; speedup 1.0000x reference)
//
#include <hip/hip_runtime.h>

#define BB 512
#define TT 1024
#define KK 48
#define NINF (-1e30f)

// One block per batch. Wave 0: forward (log-partition + gold score -> ws[b]).
// Wave 1: Viterbi (backpointers in LDS, backtrack, write tags to out[1..]).
__global__ __launch_bounds__(128, 1) void crf_main(
    const float* __restrict__ em,    // [B][T][K]
    const int*   __restrict__ tags,  // [B][T]
    const float* __restrict__ st,    // [K]
    const float* __restrict__ en,    // [K]
    const float* __restrict__ tr,    // [K][K]
    float* __restrict__ out,         // [1 + B*T]
    float* __restrict__ ws)          // [B]
{
    __shared__ float s_trans[KK * KK];          // 9216 B (uniform score lookups)
    __shared__ unsigned char s_bp[TT][KK];      // 49152 B (row 0 unused)
    __shared__ unsigned char s_path[TT];        // 1024 B
    __shared__ float s_ea[64];                  // fwd broadcast buffer
    __shared__ float s_av[64];                  // viterbi broadcast buffer

    const int b    = blockIdx.x;
    const int tid  = threadIdx.x;
    const int lane = tid & 63;
    const int wid  = tid >> 6;

    // stage transitions into LDS (both waves)
    for (int i = tid; i < KK * KK; i += 128) s_trans[i] = tr[i];
    __syncthreads();

    const float* emb = em + (size_t)b * TT * KK;
    const int*   tgb = tags + (size_t)b * TT;

    // sequence length (mask is a contiguous prefix)
    int cnt = 0;
    for (int t = lane; t < TT; t += 64) cnt += (tgb[t] > -1) ? 1 : 0;
#pragma unroll
    for (int off = 32; off >= 1; off >>= 1) cnt += __shfl_xor(cnt, off);
    const int len = cnt;  // >= 1

    const bool act = lane < KK;
    const int  jj  = act ? lane : (KK - 1);

    if (wid == 0) {
        // ---------------- forward: loss partial ----------------
        float eTc[KK];  // exp(T[:, j]) register column
#pragma unroll
        for (int i = 0; i < KK; ++i) eTc[i] = __expf(tr[i * KK + jj]);

        float e0    = emb[jj];
        float alpha = act ? (st[jj] + e0) : NINF;
        int   tp    = tgb[0];
        float score = st[tp] + __shfl(e0, tp);

        float e_cur = 0.f; int tg_cur = 0;
        if (len > 1) { e_cur = emb[KK + jj]; tg_cur = tgb[1]; }

        for (int t = 1; t < len; ++t) {
            float e_nxt = 0.f; int tg_nxt = 0;
            if (t + 1 < len) { e_nxt = emb[(t + 1) * KK + jj]; tg_nxt = tgb[t + 1]; }

            // global row max
            float m = alpha;  // inactive lanes hold NINF
#pragma unroll
            for (int off = 32; off >= 1; off >>= 1) m = fmaxf(m, __shfl_xor(m, off));
            float ea = act ? __expf(alpha - m) : 0.f;
            s_ea[lane] = ea;
            float z = 0.f;
#pragma unroll
            for (int q = 0; q < 12; ++q) {
                float4 v = ((const float4*)s_ea)[q];
                z = fmaf(v.x, eTc[4 * q + 0], z);
                z = fmaf(v.y, eTc[4 * q + 1], z);
                z = fmaf(v.z, eTc[4 * q + 2], z);
                z = fmaf(v.w, eTc[4 * q + 3], z);
            }
            alpha = act ? (m + __logf(z) + e_cur) : NINF;

            // gold path score (uniform across lanes)
            score += s_trans[tp * KK + tg_cur] + __shfl(e_cur, tg_cur);
            tp = tg_cur; e_cur = e_nxt; tg_cur = tg_nxt;
        }
        score += en[tp];

        // log_z = logsumexp(alpha + end)
        float v = act ? (alpha + en[jj]) : NINF;
        float M = v;
#pragma unroll
        for (int off = 32; off >= 1; off >>= 1) M = fmaxf(M, __shfl_xor(M, off));
        float sx = act ? __expf(v - M) : 0.f;
#pragma unroll
        for (int off = 32; off >= 1; off >>= 1) sx += __shfl_xor(sx, off);
        float logz = M + __logf(sx);
        if (lane == 0) ws[b] = score - logz;
    } else {
        // ---------------- viterbi ----------------
        float Tc[KK];  // raw T[:, j] register column
#pragma unroll
        for (int i = 0; i < KK; ++i) Tc[i] = tr[i * KK + jj];

        float a = act ? (st[jj] + emb[jj]) : NINF;

        float e_cur = 0.f;
        if (len > 1) e_cur = emb[KK + jj];

        for (int t = 1; t < len; ++t) {
            float e_nxt = 0.f;
            if (t + 1 < len) e_nxt = emb[(t + 1) * KK + jj];

            s_av[lane] = a;

            // blocked argmax: strict > within ascending i preserves
            // first-occurrence ties; merge prefers lower block on equality.
#define ARGMAX_BLOCK(BLK, BBV, BIV)                                          \
            float BBV = NINF; int BIV = (BLK) * 12;                          \
            _Pragma("unroll")                                                \
            for (int q = 0; q < 3; ++q) {                                    \
                float4 v = ((const float4*)s_av)[(BLK) * 3 + q];             \
                int base = (BLK) * 12 + q * 4;                               \
                float x;                                                     \
                x = v.x + Tc[base + 0]; if (x > BBV) { BBV = x; BIV = base + 0; } \
                x = v.y + Tc[base + 1]; if (x > BBV) { BBV = x; BIV = base + 1; } \
                x = v.z + Tc[base + 2]; if (x > BBV) { BBV = x; BIV = base + 2; } \
                x = v.w + Tc[base + 3]; if (x > BBV) { BBV = x; BIV = base + 3; } \
            }
            ARGMAX_BLOCK(0, b0, i0)
            ARGMAX_BLOCK(1, b1, i1)
            ARGMAX_BLOCK(2, b2, i2)
            ARGMAX_BLOCK(3, b3, i3)
#undef ARGMAX_BLOCK
            float bb = b0; int bi = i0;
            if (b1 > bb) { bb = b1; bi = i1; }
            if (b2 > bb) { bb = b2; bi = i2; }
            if (b3 > bb) { bb = b3; bi = i3; }

            a = act ? (bb + e_cur) : NINF;
            if (act) s_bp[t][lane] = (unsigned char)bi;
            e_cur = e_nxt;
        }

        // best last tag = argmax(alpha + end), first occurrence
        float v = act ? (a + en[jj]) : NINF;
        float M = v;
#pragma unroll
        for (int off = 32; off >= 1; off >>= 1) M = fmaxf(M, __shfl_xor(M, off));
        unsigned long long msk = __ballot(v == M);
        int cur = __ffsll(msk) - 1;

        // backtrack through LDS backpointers (uniform across lanes)
        s_path[len - 1] = (unsigned char)cur;
        for (int t = len - 1; t >= 1; --t) {
            cur = s_bp[t][cur];
            s_path[t - 1] = (unsigned char)cur;
        }

        // write tags (as floats; -1 where masked)
        float* ob = out + 1 + (size_t)b * TT;
        for (int t = lane; t < TT; t += 64)
            ob[t] = (t < len) ? (float)s_path[t] : -1.0f;
    }
}

__global__ __launch_bounds__(512) void loss_reduce(const float* __restrict__ ws,
                                                   float* __restrict__ out)
{
    __shared__ float sh[8];
    const int lane = threadIdx.x & 63;
    const int w    = threadIdx.x >> 6;
    float s = ws[threadIdx.x];  // B == 512 == blockDim
#pragma unroll
    for (int off = 32; off >= 1; off >>= 1) s += __shfl_xor(s, off);
    if (lane == 0) sh[w] = s;
    __syncthreads();
    if (threadIdx.x == 0) {
        float tot = 0.f;
        for (int i = 0; i < 8; ++i) tot += sh[i];
        out[0] = -tot;
    }
}

extern "C" void kernel_launch(void* const* d_in, const int* in_sizes, int n_in,
                              void* d_out, int out_size, void* d_ws, size_t ws_size,
                              hipStream_t stream)
{
    const float* em   = (const float*)d_in[0];
    const int*   tags = (const int*)d_in[1];
    const float* st   = (const float*)d_in[2];
    const float* en   = (const float*)d_in[3];
    const float* tr   = (const float*)d_in[4];
    float* out = (float*)d_out;
    float* wsf = (float*)d_ws;

    hipLaunchKernelGGL(crf_main, dim3(BB), dim3(128), 0, stream,
                       em, tags, st, en, tr, out, wsf);
    hipLaunchKernelGGL(loss_reduce, dim3(1), dim3(512), 0, stream, wsf, out);
}

// Round 2
// 629.966 us; speedup vs baseline: 1.2638x; 1.2638x over previous
//
#include <hip/hip_runtime.h>

#define BB 512
#define TT 1024
#define KK 48
#define NINF (-1e30f)

__device__ __forceinline__ float rlane(float v, int l) {
    return __int_as_float(__builtin_amdgcn_readlane(__float_as_int(v), l));
}
__device__ __forceinline__ float rfirst(float v) {
    return __int_as_float(__builtin_amdgcn_readfirstlane(__float_as_int(v)));
}

// One block per batch. Wave 0: forward (log-partition + gold score -> ws[b]).
// Wave 1: Viterbi (backpointers in LDS, backtrack, write tags to out[1..]).
// No __syncthreads anywhere: waves are independent; s_bp used by wave 1 only.
__global__ __launch_bounds__(128, 1) void crf_main(
    const float* __restrict__ em,    // [B][T][K]
    const int*   __restrict__ tags,  // [B][T]
    const float* __restrict__ st,    // [K]
    const float* __restrict__ en,    // [K]
    const float* __restrict__ tr,    // [K][K]
    float* __restrict__ out,         // [1 + B*T]
    float* __restrict__ ws)          // [B]
{
    __shared__ unsigned char s_bp[TT][KK];      // 49152 B (row 0 unused)
    __shared__ unsigned char s_path[TT];        // 1024 B

    const int b    = blockIdx.x;
    const int tid  = threadIdx.x;
    const int lane = tid & 63;
    const int wid  = tid >> 6;

    const float* emb = em + (size_t)b * TT * KK;
    const int*   tgb = tags + (size_t)b * TT;

    // sequence length (mask is a contiguous prefix)
    int cnt = 0;
    for (int t = lane; t < TT; t += 64) cnt += (tgb[t] > -1) ? 1 : 0;
#pragma unroll
    for (int off = 32; off >= 1; off >>= 1) cnt += __shfl_xor(cnt, off);
    const int len = cnt;  // >= 1

    const bool act = lane < KK;
    const int  jj  = act ? lane : (KK - 1);

    if (wid == 0) {
        // ---- gold path score: pure gather, t-parallel across lanes ----
        float sc = 0.f;
        for (int t = lane; t < len; t += 64) {
            int tg = tgb[t];
            sc += emb[t * KK + tg];
            if (t > 0) sc += tr[tgb[t - 1] * KK + tg];
        }
#pragma unroll
        for (int off = 32; off >= 1; off >>= 1) sc += __shfl_xor(sc, off);
        float score = sc + st[tgb[0]] + en[tgb[len - 1]];  // lane-uniform

        // ---- forward scan: log-partition only ----
        float eTc[KK];  // exp(T[:, j]) register column
#pragma unroll
        for (int i = 0; i < KK; ++i) eTc[i] = __expf(tr[i * KK + jj]);

        float a = act ? (st[jj] + emb[jj]) : NINF;
        float e_cur = (len > 1) ? emb[KK + jj] : 0.f;

        for (int t = 1; t < len; ++t) {
            float e_nxt = (t + 1 < len) ? emb[(t + 1) * KK + jj] : 0.f;

            // center = lane0 alpha (spread across lanes bounded by ~12,
            // so exp args stay in [-15, 15]; exact max not needed)
            float c  = rfirst(a);
            float ea = __expf(a - c);  // inactive lanes: exp(-inf)=0, never read

            float z0 = 0.f, z1 = 0.f, z2 = 0.f, z3 = 0.f;
#pragma unroll
            for (int q = 0; q < 12; ++q) {
                z0 = fmaf(rlane(ea, 4 * q + 0), eTc[4 * q + 0], z0);
                z1 = fmaf(rlane(ea, 4 * q + 1), eTc[4 * q + 1], z1);
                z2 = fmaf(rlane(ea, 4 * q + 2), eTc[4 * q + 2], z2);
                z3 = fmaf(rlane(ea, 4 * q + 3), eTc[4 * q + 3], z3);
            }
            a = act ? (c + __logf((z0 + z1) + (z2 + z3)) + e_cur) : NINF;
            e_cur = e_nxt;
        }

        // log_z = logsumexp(alpha + end)
        float v = act ? (a + en[jj]) : NINF;
        float M = v;
#pragma unroll
        for (int off = 32; off >= 1; off >>= 1) M = fmaxf(M, __shfl_xor(M, off));
        float sx = act ? __expf(v - M) : 0.f;
#pragma unroll
        for (int off = 32; off >= 1; off >>= 1) sx += __shfl_xor(sx, off);
        float logz = M + __logf(sx);
        if (lane == 0) ws[b] = score - logz;
    } else {
        // ---------------- viterbi (bit-exact vs reference) ----------------
        float Tc[KK];  // raw T[:, j] register column
#pragma unroll
        for (int i = 0; i < KK; ++i) Tc[i] = tr[i * KK + jj];

        float a = act ? (st[jj] + emb[jj]) : NINF;
        float e_cur = (len > 1) ? emb[KK + jj] : 0.f;

        for (int t = 1; t < len; ++t) {
            float e_nxt = (t + 1 < len) ? emb[(t + 1) * KK + jj] : 0.f;

            // broadcast alpha via readlane; candidates x[i] = a_i + T[i][j]
            float x[KK];
#pragma unroll
            for (int i = 0; i < KK; ++i) x[i] = rlane(a, i) + Tc[i];

            // max value: 3-way tree (48 -> 16 -> 6 -> 2 -> 1), exact
            float l1[16];
#pragma unroll
            for (int q = 0; q < 16; ++q)
                l1[q] = fmaxf(fmaxf(x[3 * q], x[3 * q + 1]), x[3 * q + 2]);
            float l2[6];
#pragma unroll
            for (int q = 0; q < 5; ++q)
                l2[q] = fmaxf(fmaxf(l1[3 * q], l1[3 * q + 1]), l1[3 * q + 2]);
            l2[5] = l1[15];
            float l3a = fmaxf(fmaxf(l2[0], l2[1]), l2[2]);
            float l3b = fmaxf(fmaxf(l2[3], l2[4]), l2[5]);
            float M = fmaxf(l3a, l3b);

            // first-occurrence argmax: blocked descending scan, min-merge
            int bi0 = 255, bi1 = 255, bi2 = 255, bi3 = 255;
#pragma unroll
            for (int i = 11; i >= 0; --i) {
                bi0 = (x[i]      == M) ? (i)      : bi0;
                bi1 = (x[i + 12] == M) ? (i + 12) : bi1;
                bi2 = (x[i + 24] == M) ? (i + 24) : bi2;
                bi3 = (x[i + 36] == M) ? (i + 36) : bi3;
            }
            int bi = min(min(bi0, bi1), min(bi2, bi3));

            a = act ? (M + e_cur) : NINF;
            if (act) s_bp[t][lane] = (unsigned char)bi;
            e_cur = e_nxt;
        }

        // best last tag = argmax(alpha + end), first occurrence
        float v = act ? (a + en[jj]) : NINF;
        float M = v;
#pragma unroll
        for (int off = 32; off >= 1; off >>= 1) M = fmaxf(M, __shfl_xor(M, off));
        unsigned long long msk = __ballot(v == M);
        int cur = __ffsll(msk) - 1;

        // backtrack through LDS backpointers (uniform across lanes)
        s_path[len - 1] = (unsigned char)cur;
        for (int t = len - 1; t >= 1; --t) {
            cur = s_bp[t][cur];
            s_path[t - 1] = (unsigned char)cur;
        }

        // write tags (as floats; -1 where masked)
        float* ob = out + 1 + (size_t)b * TT;
        for (int t = lane; t < TT; t += 64)
            ob[t] = (t < len) ? (float)s_path[t] : -1.0f;
    }
}

__global__ __launch_bounds__(512) void loss_reduce(const float* __restrict__ ws,
                                                   float* __restrict__ out)
{
    __shared__ float sh[8];
    const int lane = threadIdx.x & 63;
    const int w    = threadIdx.x >> 6;
    float s = ws[threadIdx.x];  // B == 512 == blockDim
#pragma unroll
    for (int off = 32; off >= 1; off >>= 1) s += __shfl_xor(s, off);
    if (lane == 0) sh[w] = s;
    __syncthreads();
    if (threadIdx.x == 0) {
        float tot = 0.f;
        for (int i = 0; i < 8; ++i) tot += sh[i];
        out[0] = -tot;
    }
}

extern "C" void kernel_launch(void* const* d_in, const int* in_sizes, int n_in,
                              void* d_out, int out_size, void* d_ws, size_t ws_size,
                              hipStream_t stream)
{
    const float* em   = (const float*)d_in[0];
    const int*   tags = (const int*)d_in[1];
    const float* st   = (const float*)d_in[2];
    const float* en   = (const float*)d_in[3];
    const float* tr   = (const float*)d_in[4];
    float* out = (float*)d_out;
    float* wsf = (float*)d_ws;

    hipLaunchKernelGGL(crf_main, dim3(BB), dim3(128), 0, stream,
                       em, tags, st, en, tr, out, wsf);
    hipLaunchKernelGGL(loss_reduce, dim3(1), dim3(512), 0, stream, wsf, out);
}